// Round 4
// baseline (249.303 us; speedup 1.0000x reference)
//
#include <hip/hip_runtime.h>
#include <hip/hip_bf16.h>
#include <cstdint>

typedef __bf16 bf16_t;
typedef __bf16 bf16x8 __attribute__((ext_vector_type(8)));
typedef __bf16 bf16x4 __attribute__((ext_vector_type(4)));
typedef __bf16 bf16x2 __attribute__((ext_vector_type(2)));
typedef float  f32x4  __attribute__((ext_vector_type(4)));
typedef float  f32x16 __attribute__((ext_vector_type(16)));
typedef unsigned uint4v __attribute__((ext_vector_type(4)));

#define AS1 __attribute__((address_space(1)))
#define AS3 __attribute__((address_space(3)))

// async global->LDS, 16B per lane; LDS dest is wave-uniform base + lane*16
static __device__ __forceinline__ void gld_lds16(const void* g, void* l) {
  __builtin_amdgcn_global_load_lds((AS1 void*)g, (AS3 void*)l, 16, 0, 0);
}

// pack two f32 -> one u32 of 2 bf16 (compiler emits cvt_pk)
static __device__ __forceinline__ unsigned pk2(float a, float b) {
  bf16x2 v; v[0] = (bf16_t)a; v[1] = (bf16_t)b;
  return __builtin_bit_cast(unsigned, v);
}

static __device__ __forceinline__ bf16x8 cat44(bf16x4 a, bf16x4 b) {
  bf16x8 r;
  r[0] = a[0]; r[1] = a[1]; r[2] = a[2]; r[3] = a[3];
  r[4] = b[0]; r[5] = b[1]; r[6] = b[2]; r[7] = b[3];
  return r;
}

// ---------------- convert / transpose ----------------

__global__ __launch_bounds__(256) void convert_f32_bf16(const float* __restrict__ in,
                                                        bf16_t* __restrict__ out, int n4) {
  int i = blockIdx.x * 256 + threadIdx.x;
  if (i < n4) {
    float4 v = ((const float4*)in)[i];
    bf16x4 o;
    o[0] = (bf16_t)v.x; o[1] = (bf16_t)v.y; o[2] = (bf16_t)v.z; o[3] = (bf16_t)v.w;
    *(bf16x4*)(out + (size_t)i * 4) = o;
  }
}

// in [K][N] f32 -> out [N][K] bf16
__global__ __launch_bounds__(256) void transpose_w(const float* __restrict__ in,
                                                   bf16_t* __restrict__ out, int K, int N) {
  __shared__ float tile[32][33];
  const int t = threadIdx.x, c = t & 31, r0 = t >> 5;
  const int bx = blockIdx.x, by = blockIdx.y;
#pragma unroll
  for (int i = 0; i < 4; ++i) {
    int r = r0 + i * 8;
    tile[r][c] = in[(size_t)(by * 32 + r) * N + bx * 32 + c];
  }
  __syncthreads();
#pragma unroll
  for (int i = 0; i < 4; ++i) {
    int r = r0 + i * 8;
    out[(size_t)(bx * 32 + r) * K + by * 32 + c] = (bf16_t)tile[c][r];
  }
}

// ---------------- 128x128 bf16 GEMM core (m97 structure, BK=32) ----------------
template <int KDIM>
static __device__ __forceinline__ void gemm128_compute(const bf16_t* __restrict__ A,
                                                       const bf16_t* __restrict__ Bt,
                                                       bf16_t* lA, bf16_t* lB,
                                                       f32x4 acc[4][4]) {
  const int t = threadIdx.x;
  const int lr = t & 15, g = (t >> 4) & 3;
  const int w = t >> 6, wr = w >> 1, wc = w & 1;
  const int bm = blockIdx.x, bn = blockIdx.y;

  for (int kt = 0; kt < KDIM; kt += 32) {
    __syncthreads();
#pragma unroll
    for (int c2 = 0; c2 < 2; ++c2) {
      const int idx = c2 * 256 + t;
      const int row = idx >> 2, cb = idx & 3;
      const int ldsoff = ((t & 192) + c2 * 256) * 8;
      gld_lds16(A  + (size_t)(bm * 128 + row) * KDIM + kt + cb * 8, lA + ldsoff);
      gld_lds16(Bt + (size_t)(bn * 128 + row) * KDIM + kt + cb * 8, lB + ldsoff);
    }
    __syncthreads();
    bf16x8 af[4], bv[4];
#pragma unroll
    for (int mi = 0; mi < 4; ++mi)
      af[mi] = *(const bf16x8*)(lA + (wr * 64 + mi * 16 + lr) * 32 + g * 8);
#pragma unroll
    for (int ni = 0; ni < 4; ++ni)
      bv[ni] = *(const bf16x8*)(lB + (wc * 64 + ni * 16 + lr) * 32 + g * 8);
#pragma unroll
    for (int mi = 0; mi < 4; ++mi)
#pragma unroll
      for (int ni = 0; ni < 4; ++ni)
        acc[mi][ni] = __builtin_amdgcn_mfma_f32_16x16x32_bf16(af[mi], bv[ni], acc[mi][ni], 0, 0, 0);
  }
}

// GEMM1: qkv = x @ Wqkv ; scatter into Q [bh][s][d], K [bh][s][d], Vt [bh][d][s]
__global__ __launch_bounds__(256) void gemm_qkv_k(const bf16_t* __restrict__ xb,
                                                  const bf16_t* __restrict__ wt,
                                                  bf16_t* __restrict__ Qo,
                                                  bf16_t* __restrict__ Ko,
                                                  bf16_t* __restrict__ Vto) {
  __shared__ bf16_t lA[128 * 32], lB[128 * 32];
  f32x4 acc[4][4] = {};
  gemm128_compute<1024>(xb, wt, lA, lB, acc);
  const int t = threadIdx.x, lr = t & 15, g = (t >> 4) & 3, w = t >> 6, wr = w >> 1, wc = w & 1;
  const int row0 = blockIdx.x * 128 + wr * 64, col0 = blockIdx.y * 128 + wc * 64;
#pragma unroll
  for (int mi = 0; mi < 4; ++mi) {
    const int row = row0 + mi * 16 + g * 4;
    const int b = row >> 11, s = row & 2047;
#pragma unroll
    for (int ni = 0; ni < 4; ++ni) {
      const int col = col0 + ni * 16 + lr;
      const int t3 = col >> 10, rem = col & 1023, h = rem >> 6, d = rem & 63;
      const int bh = b * 16 + h;
#pragma unroll
      for (int r = 0; r < 4; ++r) {
        const bf16_t v = (bf16_t)acc[mi][ni][r];
        if (t3 == 0)      Qo[((size_t)bh * 2048 + s + r) * 64 + d] = v;
        else if (t3 == 1) Ko[((size_t)bh * 2048 + s + r) * 64 + d] = v;
        else              Vto[((size_t)bh * 64 + d) * 2048 + s + r] = v;
      }
    }
  }
}

// GEMM3: out = attn @ Wo  (fp32 out)
__global__ __launch_bounds__(256) void gemm_o_k(const bf16_t* __restrict__ attn,
                                                const bf16_t* __restrict__ wot,
                                                float* __restrict__ out) {
  __shared__ bf16_t lA[128 * 32], lB[128 * 32];
  f32x4 acc[4][4] = {};
  gemm128_compute<1024>(attn, wot, lA, lB, acc);
  const int t = threadIdx.x, lr = t & 15, g = (t >> 4) & 3, w = t >> 6, wr = w >> 1, wc = w & 1;
  const int row0 = blockIdx.x * 128 + wr * 64, col0 = blockIdx.y * 128 + wc * 64;
#pragma unroll
  for (int mi = 0; mi < 4; ++mi) {
    const int row = row0 + mi * 16 + g * 4;
#pragma unroll
    for (int ni = 0; ni < 4; ++ni) {
      const int col = col0 + ni * 16 + lr;
#pragma unroll
      for (int r = 0; r < 4; ++r)
        out[(size_t)(row + r) * 1024 + col] = acc[mi][ni][r];
    }
  }
}

// ---------------- flash attention (swapped-QK^T 32x32, zero-shuffle PV) -------
// grid (16, 32): x = 128-row q block (4 waves * 32 q), y = bh.
// Q,K: [bh][2048][64] ; Vt: [bh][64][2048] ; Ao: [b][s][h*64+d]  (all bf16)
// Lane (ql=l&31, hi=l>>5) holds s[r] = S[q=ql][kv=crow(r,hi)],
// crow(r,hi) = (r&3) + 8*(r>>2) + 4*hi  (HW-verified 32x32 C/D layout).
// PV needs P and V element-aligned per (hi,e) only — internal k-map cancels —
// so load V in crow order (two bf16x4 per fragment) and pack P with NO
// cross-lane movement.
__global__ __launch_bounds__(256) void attn_k(const bf16_t* __restrict__ Q,
                                              const bf16_t* __restrict__ K,
                                              const bf16_t* __restrict__ Vt,
                                              bf16_t* __restrict__ Ao) {
  __shared__ __align__(16) bf16_t obuf[4][2048];
  const int t = threadIdx.x, w = t >> 6, l = t & 63;
  const int ql = l & 31, hi = l >> 5;
  const int bh = blockIdx.y, b = bh >> 4, h = bh & 15;
  const bf16_t* Qb = Q  + (size_t)bh * 2048 * 64;
  const bf16_t* Kb = K  + (size_t)bh * 2048 * 64;
  const bf16_t* Vb = Vt + (size_t)bh * 64 * 2048;
  const int q0 = blockIdx.x * 128 + w * 32;
  const float cs = 0.18033688011112042f;  // log2(e)/sqrt(64)

  // Q B-frags: lane holds Q[q0+ql][16t + hi*8 + e] (same bytes as K A-frag ->
  // internal k-map cancels in QK^T)
  const bf16_t* qp = Qb + (size_t)(q0 + ql) * 64 + hi * 8;
  bf16x8 qf0 = *(const bf16x8*)(qp);
  bf16x8 qf1 = *(const bf16x8*)(qp + 16);
  bf16x8 qf2 = *(const bf16x8*)(qp + 32);
  bf16x8 qf3 = *(const bf16x8*)(qp + 48);

  const bf16_t* kq = Kb + (size_t)ql * 64 + hi * 8;
  // V rows in crow order: base includes +4*hi
  const bf16_t* vrow0 = Vb + (size_t)ql * 2048 + hi * 4;        // d = ql
  const bf16_t* vrow1 = vrow0 + 32 * 2048;                      // d = 32 + ql

  f32x16 ot0 = {}, ot1 = {};
  float m = -1e30f, ls = 0.0f;

  // prefetch K tile 0
  bf16x8 kf0 = *(const bf16x8*)(kq);
  bf16x8 kf1 = *(const bf16x8*)(kq + 16);
  bf16x8 kf2 = *(const bf16x8*)(kq + 32);
  bf16x8 kf3 = *(const bf16x8*)(kq + 48);

  for (int jt = 0; jt < 64; ++jt) {
    const int kv0 = jt * 32;
    // V loads in crow order: kv = kv0 + {0,8,16,24} + 4*hi, 4 elems each
    bf16x4 va00 = *(const bf16x4*)(vrow0 + kv0);       // slice kv 0..15, e0..3
    bf16x4 va01 = *(const bf16x4*)(vrow0 + kv0 + 8);   //               e4..7
    bf16x4 va10 = *(const bf16x4*)(vrow0 + kv0 + 16);  // slice kv16..31, e0..3
    bf16x4 va11 = *(const bf16x4*)(vrow0 + kv0 + 24);  //                e4..7
    bf16x4 vb00 = *(const bf16x4*)(vrow1 + kv0);
    bf16x4 vb01 = *(const bf16x4*)(vrow1 + kv0 + 8);
    bf16x4 vb10 = *(const bf16x4*)(vrow1 + kv0 + 16);
    bf16x4 vb11 = *(const bf16x4*)(vrow1 + kv0 + 24);

    // S^T[kv][q], raw (unscaled)
    f32x16 s = {};
    s = __builtin_amdgcn_mfma_f32_32x32x16_bf16(kf0, qf0, s, 0, 0, 0);
    s = __builtin_amdgcn_mfma_f32_32x32x16_bf16(kf1, qf1, s, 0, 0, 0);
    s = __builtin_amdgcn_mfma_f32_32x32x16_bf16(kf2, qf2, s, 0, 0, 0);
    s = __builtin_amdgcn_mfma_f32_32x32x16_bf16(kf3, qf3, s, 0, 0, 0);

    // prefetch next K tile
    {
      const bf16_t* kn = kq + (size_t)(jt < 63 ? kv0 + 32 : kv0) * 64;
      kf0 = *(const bf16x8*)(kn);
      kf1 = *(const bf16x8*)(kn + 16);
      kf2 = *(const bf16x8*)(kn + 32);
      kf3 = *(const bf16x8*)(kn + 48);
    }

    // row max over 16 local kv + partner half
    float pm = s[0];
#pragma unroll
    for (int r = 1; r < 16; ++r) pm = fmaxf(pm, s[r]);
    pm = fmaxf(pm, __shfl_xor(pm, 32));
    const float cand = pm * cs;
    if (__any(cand - m > 8.0f)) {   // defer-max (T13): rescale rarely
      const float mn = fmaxf(m, cand);
      const float alpha = exp2f(m - mn);
      m = mn;
      ls *= alpha;
#pragma unroll
      for (int r = 0; r < 16; ++r) { ot0[r] *= alpha; ot1[r] *= alpha; }
    }

    // p = exp2(s*cs - m), row-sum
    float p[16];
    float rs = 0.0f;
#pragma unroll
    for (int r = 0; r < 16; ++r) {
      p[r] = exp2f(fmaf(s[r], cs, -m));
      rs += p[r];
    }
    ls += rs + __shfl_xor(rs, 32);

    // pack P in crow order: element e of pf0 carries kv = crow(e,hi);
    // pf1 carries 16 + crow(e,hi). Matches V's crow-order load exactly.
    unsigned w0 = pk2(p[0],  p[1]),  w1 = pk2(p[2],  p[3]);
    unsigned w2 = pk2(p[4],  p[5]),  w3 = pk2(p[6],  p[7]);
    unsigned w4 = pk2(p[8],  p[9]),  w5 = pk2(p[10], p[11]);
    unsigned w6 = pk2(p[12], p[13]), w7 = pk2(p[14], p[15]);
    uint4v u0 = {w0, w1, w2, w3};
    uint4v u1 = {w4, w5, w6, w7};
    bf16x8 pf0 = __builtin_bit_cast(bf16x8, u0);
    bf16x8 pf1 = __builtin_bit_cast(bf16x8, u1);

    // O^T[d][q] += V^T * P^T   (element-aligned per (hi,e) by construction)
    ot0 = __builtin_amdgcn_mfma_f32_32x32x16_bf16(cat44(va00, va01), pf0, ot0, 0, 0, 0);
    ot0 = __builtin_amdgcn_mfma_f32_32x32x16_bf16(cat44(va10, va11), pf1, ot0, 0, 0, 0);
    ot1 = __builtin_amdgcn_mfma_f32_32x32x16_bf16(cat44(vb00, vb01), pf0, ot1, 0, 0, 0);
    ot1 = __builtin_amdgcn_mfma_f32_32x32x16_bf16(cat44(vb10, vb11), pf1, ot1, 0, 0, 0);
  }

  // epilogue: normalize, transpose via swizzled LDS, coalesced bf16 store
  const float inv = 1.0f / ls;
  bf16_t* ob = &obuf[w][0];
#pragma unroll
  for (int rg = 0; rg < 4; ++rg) {
    const int d0 = rg * 8 + hi * 4;
    bf16x4 vv;
    vv[0] = (bf16_t)(ot0[4 * rg + 0] * inv);
    vv[1] = (bf16_t)(ot0[4 * rg + 1] * inv);
    vv[2] = (bf16_t)(ot0[4 * rg + 2] * inv);
    vv[3] = (bf16_t)(ot0[4 * rg + 3] * inv);
    const int byteo = ql * 128 + ((d0 * 2) ^ ((ql & 7) << 4));
    *(bf16x4*)((char*)ob + byteo) = vv;
  }
#pragma unroll
  for (int rg = 0; rg < 4; ++rg) {
    const int d0 = 32 + rg * 8 + hi * 4;
    bf16x4 vv;
    vv[0] = (bf16_t)(ot1[4 * rg + 0] * inv);
    vv[1] = (bf16_t)(ot1[4 * rg + 1] * inv);
    vv[2] = (bf16_t)(ot1[4 * rg + 2] * inv);
    vv[3] = (bf16_t)(ot1[4 * rg + 3] * inv);
    const int byteo = ql * 128 + ((d0 * 2) ^ ((ql & 7) << 4));
    *(bf16x4*)((char*)ob + byteo) = vv;
  }
  __syncthreads();
#pragma unroll
  for (int i = 0; i < 4; ++i) {
    const int c = i * 64 + l;
    const int qq = c >> 3, ch = c & 7;
    const int byteo = qq * 128 + ((ch * 16) ^ ((qq & 7) << 4));
    bf16x8 vv = *(const bf16x8*)((char*)ob + byteo);
    *(bf16x8*)(Ao + (size_t)(b * 2048 + q0 + qq) * 1024 + h * 64 + ch * 8) = vv;
  }
}

// ---------------- launcher ----------------

extern "C" void kernel_launch(void* const* d_in, const int* in_sizes, int n_in,
                              void* d_out, int out_size, void* d_ws, size_t ws_size,
                              hipStream_t stream) {
  const float* x    = (const float*)d_in[0];  // [2,2048,1024]
  const float* wqkv = (const float*)d_in[1];  // [1024,3072]
  const float* wo   = (const float*)d_in[2];  // [1024,1024]
  float* out = (float*)d_out;

  char* ws = (char*)d_ws;
  bf16_t* xb    = (bf16_t*)(ws);                       // 8 MB  [4096][1024]
  bf16_t* wqkvT = (bf16_t*)(ws + (size_t)(8u  << 20)); // 6 MB  [3072][1024]
  bf16_t* woT   = (bf16_t*)(ws + (size_t)(14u << 20)); // 2 MB  [1024][1024]
  bf16_t* Qb    = (bf16_t*)(ws + (size_t)(16u << 20)); // 8 MB  [32][2048][64]
  bf16_t* Kb    = (bf16_t*)(ws + (size_t)(24u << 20)); // 8 MB
  bf16_t* Vtb   = (bf16_t*)(ws + (size_t)(32u << 20)); // 8 MB  [32][64][2048]
  bf16_t* attn  = (bf16_t*)(ws + (size_t)(40u << 20)); // 8 MB  [4096][1024]

  convert_f32_bf16<<<4096, 256, 0, stream>>>(x, xb, 4096 * 1024 / 4);
  transpose_w<<<dim3(96, 32), 256, 0, stream>>>(wqkv, wqkvT, 1024, 3072);
  transpose_w<<<dim3(32, 32), 256, 0, stream>>>(wo, woT, 1024, 1024);
  gemm_qkv_k<<<dim3(32, 24), 256, 0, stream>>>(xb, wqkvT, Qb, Kb, Vtb);
  attn_k<<<dim3(16, 32), 256, 0, stream>>>(Qb, Kb, Vtb, attn);
  gemm_o_k<<<dim3(32, 8), 256, 0, stream>>>(attn, woT, out);
}